// Round 9
// baseline (344.372 us; speedup 1.0000x reference)
//
#include <hip/hip_runtime.h>
#include <hip/hip_bf16.h>
#include <hip/hip_cooperative_groups.h>

namespace cg = cooperative_groups;

#define NN 5000
#define BB 16
#define EE 40000
#define INF 128
#define HID 512
#define M1D 1024
#define EPSV 1e-5f

typedef float f4 __attribute__((ext_vector_type(4)));

__device__ __forceinline__ float dot4(f4 a, f4 b) {
    return fmaf(a.x, b.x, fmaf(a.y, b.y, fmaf(a.z, b.z, a.w * b.w)));
}
__device__ __forceinline__ f4 ntload(const float* p) {
    return __builtin_nontemporal_load((const f4*)p);
}
// DPP cross-lane (VALU, no DS pipe)
__device__ __forceinline__ float dpp_xor1(float x) {
    return __int_as_float(__builtin_amdgcn_update_dpp(0, __float_as_int(x), 0xB1, 0xF, 0xF, true));
}
__device__ __forceinline__ float dpp_xor2(float x) {
    return __int_as_float(__builtin_amdgcn_update_dpp(0, __float_as_int(x), 0x4E, 0xF, 0xF, true));
}
__device__ __forceinline__ float dpp_xor8(float x) {
    return __int_as_float(__builtin_amdgcn_update_dpp(0, __float_as_int(x), 0x128, 0xF, 0xF, true));
}

// =============== shared phase bodies (device functions) =======================

__device__ __forceinline__ void mlp_body(int blk, int tid, const float* nh,
        const float* W1, const float* b1, const float* a1, const float* g1,
        const float* be1, float* m1) {
    const int t = blk * 256 + tid;
    const int q = t & 3, idx = t >> 2;
    const int b = idx >> 10, i = idx & 1023;
    const float* hb = nh + b * HID;
    const float* wr = W1 + (size_t)i * HID;
    float acc = 0.f;
    #pragma unroll 8
    for (int ii = 0; ii < 32; ++ii) {
        const int k0 = ii * 16 + q * 4;
        acc += dot4(*(const f4*)(hb + k0), *(const f4*)(wr + k0));
    }
    acc += __shfl_xor(acc, 1); acc += __shfl_xor(acc, 2);
    if (q == 0) {
        acc += b1[i];
        float v = acc >= 0.f ? acc : a1[i] * acc;
        m1[idx] = v * (1.f / sqrtf(1.f + EPSV)) * g1[i] + be1[i];
    }
}

__device__ __forceinline__ void agg1_item(int t, const int* ei, const float* deg,
        const float* zpack, float* aggzE, float* s1E) {
    const int e = t >> 4, b = t & 15;
    const int s = ei[e], d = ei[EE + e];
    const float w = rsqrtf(1.f + deg[s]) * rsqrtf(1.f + deg[d]);
    atomicAdd(&aggzE[d * 16 + b], w * zpack[s * 16 + b]);
    if (b == 0) atomicAdd(&s1E[d], w);
}

__device__ __forceinline__ void agg2_item(int t, const int* ei, const float* deg,
        const float* zpack, const float* aggzE, float* aggz2E) {
    const int e = t >> 4, b = t & 15;
    const int s = ei[e], d = ei[EE + e];
    const float degs = deg[s];
    const float d2s = 1.f / (1.f + degs);
    const float w = rsqrtf(1.f + degs) * rsqrtf(1.f + deg[d]);
    const float A1s = aggzE[s * 16 + b] + d2s * zpack[s * 16 + b];
    atomicAdd(&aggz2E[d * 16 + b], w * A1s);
}

__device__ __forceinline__ void stream_body(int blk, int tid,
        float (*accs)[80][16],
        const float* W2, const float* m1, const float* b2, const float* a2,
        const float* g2, const float* be2, const float* Wo, float* ysum) {
    const int w = tid >> 6, l = tid & 63;
    const int koff = w * 256 + l * 4;
    const int n0 = blk * 5;
    const int jbase = n0 * 16;

    float4 m1r[16];
    #pragma unroll
    for (int b = 0; b < 16; ++b)
        m1r[b] = *(const float4*)(m1 + b * M1D + koff);

    const int hi0 = l & 1, hi1 = (l >> 1) & 1, hi2 = (l >> 2) & 1, hi3 = (l >> 3) & 1;
    const int brev = ((l & 1) << 3) | ((l & 2) << 1) | ((l & 4) >> 1) | ((l & 8) >> 3);

    const float* wp = W2 + (size_t)jbase * M1D + koff;
    f4 w0 = ntload(wp);
    f4 w1 = ntload(wp + M1D);
    f4 w2v = ntload(wp + 2 * M1D);
    for (int jj = 0; jj < 80; ++jj) {
        const int jn = (jj + 3 < 80) ? (jj + 3) : 79;
        const f4 wn = ntload(wp + (size_t)jn * M1D);
        float acc[16];
        #pragma unroll
        for (int b = 0; b < 16; ++b)
            acc[b] = fmaf(w0.x, m1r[b].x, fmaf(w0.y, m1r[b].y,
                     fmaf(w0.z, m1r[b].z, w0.w * m1r[b].w)));
        float r8[8];
        #pragma unroll
        for (int i = 0; i < 8; ++i) {
            float keep = hi0 ? acc[8 + i] : acc[i];
            float send = hi0 ? acc[i]     : acc[8 + i];
            r8[i] = keep + dpp_xor1(send);
        }
        float r4[4];
        #pragma unroll
        for (int i = 0; i < 4; ++i) {
            float keep = hi1 ? r8[4 + i] : r8[i];
            float send = hi1 ? r8[i]     : r8[4 + i];
            r4[i] = keep + dpp_xor2(send);
        }
        float r2[2];
        #pragma unroll
        for (int i = 0; i < 2; ++i) {
            float keep = hi2 ? r4[2 + i] : r4[i];
            float send = hi2 ? r4[i]     : r4[2 + i];
            r2[i] = keep + __shfl_xor(send, 4, 64);
        }
        float keep = hi3 ? r2[1] : r2[0];
        float send = hi3 ? r2[0] : r2[1];
        float r1 = keep + dpp_xor8(send);
        r1 += __shfl_xor(r1, 16, 64);
        r1 += __shfl_xor(r1, 32, 64);
        if (l < 16) accs[w][jj][brev] = r1;
        w0 = w1; w1 = w2v; w2v = wn;
    }
    __syncthreads();

    if (tid < 80) {
        const int nl = tid >> 4, b = tid & 15;
        const float invs = 1.f / sqrtf(1.f + EPSV);
        float sum = 0.f;
        #pragma unroll
        for (int kk = 0; kk < 16; ++kk) {
            const int rloc = nl * 16 + kk;
            const int j = jbase + rloc;
            float a = accs[0][rloc][b] + accs[1][rloc][b]
                    + accs[2][rloc][b] + accs[3][rloc][b] + b2[j];
            float v = a >= 0.f ? a : a2[j] * a;
            float val = v * invs * g2[j] + be2[j];
            sum = fmaf(val, Wo[kk], sum);
        }
        ysum[n0 * 16 + tid] = sum;
    }
}

__device__ __forceinline__ void fin_item(int t, const float* ysum,
        const float* aggzE, const float* aggz2E, const float* s1E,
        const float* deg, const float* zpack, const float* cst, float* y) {
    const int n = t >> 4, b = t & 15;
    const float U = cst[0], V = cst[1], C0 = cst[2];
    const float d2 = 1.f / (1.f + deg[n]);
    const float z  = zpack[t];
    const float A1 = aggzE[t] + d2 * z;
    const float A2 = aggz2E[t] + d2 * A1;
    const float S1v = s1E[n] + d2;
    y[b * NN + n] = ysum[t] + U * A2 + V * S1v + C0;
}

// ---------------- S1: GRU | deg-atomics | consts | zpack | zero ---------------
#define GRU_BLOCKS 128
#define DEG_BLOCKS 157
#define ZPACK_BLOCKS 313
#define ZERO_BLOCKS 157

__global__ __launch_bounds__(256)
void k_s1(const int* __restrict__ ei, const float* __restrict__ x,
          const float* __restrict__ svp,
          const float* __restrict__ Wih, const float* __restrict__ bih,
          const float* __restrict__ bhh,
          const float* __restrict__ Wg1, const float* __restrict__ bg1,
          const float* __restrict__ Wg2, const float* __restrict__ bg2,
          const float* __restrict__ Wo, const float* __restrict__ bo,
          float* __restrict__ deg, float* __restrict__ nh,
          float* __restrict__ outNH, float* __restrict__ cst,
          float* __restrict__ zpack, float* __restrict__ zerobase) {
    const int blk = blockIdx.x;
    const int tid = threadIdx.x;

    if (blk < GRU_BLOCKS) {
        const int t = blk * 256 + tid;
        const int q = t & 3, idx = t >> 2;
        const int b = idx >> 9, h = idx & 511;
        const float* xb = x + b * INF;
        const float* wr = Wih + (size_t)h * INF;
        const float* wz = Wih + (size_t)(HID + h) * INF;
        const float* wg = Wih + (size_t)(2 * HID + h) * INF;
        float ir = 0.f, iz = 0.f, ig = 0.f;
        #pragma unroll 8
        for (int i = 0; i < 8; ++i) {
            const int k0 = i * 16 + q * 4;
            const f4 xv = *(const f4*)(xb + k0);
            ir += dot4(xv, *(const f4*)(wr + k0));
            iz += dot4(xv, *(const f4*)(wz + k0));
            ig += dot4(xv, *(const f4*)(wg + k0));
        }
        ir += __shfl_xor(ir, 1); ir += __shfl_xor(ir, 2);
        iz += __shfl_xor(iz, 1); iz += __shfl_xor(iz, 2);
        ig += __shfl_xor(ig, 1); ig += __shfl_xor(ig, 2);
        if (q == 0) {
            ir += bih[h]; iz += bih[HID + h]; ig += bih[2 * HID + h];
            float r  = 1.f / (1.f + expf(-(ir + bhh[h])));
            float z  = 1.f / (1.f + expf(-(iz + bhh[HID + h])));
            float nv = tanhf(ig + r * bhh[2 * HID + h]);
            float v  = (1.f - z) * nv;
            nh[idx] = v;
            outNH[idx] = v;
        }
    } else if (blk < GRU_BLOCKS + DEG_BLOCKS) {
        const int e = (blk - GRU_BLOCKS) * 256 + tid;
        if (e < EE) atomicAdd(&deg[ei[EE + e]], 1.0f);
    } else if (blk == GRU_BLOCKS + DEG_BLOCKS) {
        __shared__ float su[128], sv[128], sc[128];
        const int g = tid;
        if (g < 128) {
            float t = 0.f;
            for (int c = 0; c < 128; ++c) t = fmaf(Wg2[g * 128 + c], Wo[16 + c], t);
            su[g] = Wg1[g] * t;
            sv[g] = bg1[g] * t;
            sc[g] = bg2[g] * Wo[16 + g];
        }
        __syncthreads();
        for (int s = 64; s > 0; s >>= 1) {
            if (g < s) { su[g] += su[g + s]; sv[g] += sv[g + s]; sc[g] += sc[g + s]; }
            __syncthreads();
        }
        if (g == 0) { cst[0] = su[0]; cst[1] = sv[0]; cst[2] = sc[0] + bo[0]; }
    } else if (blk < GRU_BLOCKS + DEG_BLOCKS + 1 + ZPACK_BLOCKS) {
        const int t = (blk - (GRU_BLOCKS + DEG_BLOCKS + 1)) * 256 + tid;
        if (t < NN * BB) {
            const int n = t >> 4, b = t & 15;
            zpack[t] = svp[b * (NN * 3) + 3 * n + 2];
        }
    } else {
        const int t = (blk - (GRU_BLOCKS + DEG_BLOCKS + 1 + ZPACK_BLOCKS)) * 256 + tid;
        if (t < 2 * BB * NN / 4) ((f4*)zerobase)[t] = (f4)(0.f);
    }
}

// ---------------- cooperative path --------------------------------------------
#define COOP_BLOCKS 1000
#define MLP_BLOCKS 256
#define AGG1_BLOCKS 744
#define AGG1_PER_BLOCK 861
#define AGG2_PER_BLOCK 640

__global__ __launch_bounds__(256, 4)
void k_coop(const float* __restrict__ W2, float* m1,
            const float* __restrict__ b2, const float* __restrict__ a2,
            const float* __restrict__ g2, const float* __restrict__ be2,
            const float* __restrict__ Wo,
            const int* __restrict__ ei, const float* __restrict__ deg,
            const float* __restrict__ zpack, float* aggzE,
            float* aggz2E, float* s1E, float* ysum,
            const float* __restrict__ nh,
            const float* __restrict__ W1, const float* __restrict__ b1,
            const float* __restrict__ a1, const float* __restrict__ g1,
            const float* __restrict__ be1,
            const float* __restrict__ cst, float* __restrict__ y) {
    cg::grid_group grid = cg::this_grid();
    __shared__ float accs[4][80][16];
    const int blk = blockIdx.x;
    const int tid = threadIdx.x;

    // Phase A: MLP1 | agg1
    if (blk < MLP_BLOCKS) {
        mlp_body(blk, tid, nh, W1, b1, a1, g1, be1, m1);
    } else {
        const int base = (blk - MLP_BLOCKS) * AGG1_PER_BLOCK;
        #pragma unroll
        for (int i = 0; i < 4; ++i) {
            const int it = i * 256 + tid;
            if (it < AGG1_PER_BLOCK) {
                const int t = base + it;
                if (t < EE * BB) agg1_item(t, ei, deg, zpack, aggzE, s1E);
            }
        }
    }

    grid.sync();

    // Phase B: agg2 prologue + W2 stream
    {
        const int base = blk * AGG2_PER_BLOCK;
        #pragma unroll
        for (int i = 0; i < 3; ++i) {
            const int it = i * 256 + tid;
            if (it < AGG2_PER_BLOCK) agg2_item(base + it, ei, deg, zpack, aggzE, aggz2E);
        }
    }
    stream_body(blk, tid, accs, W2, m1, b2, a2, g2, be2, Wo, ysum);

    grid.sync();

    // Phase C: fin (each block finishes its own 80 outputs)
    if (tid < 80) fin_item(blk * 80 + tid, ysum, aggzE, aggz2E, s1E, deg, zpack, cst, y);
}

// ---------------- fallback path (proven R7 chain) -----------------------------

__global__ __launch_bounds__(256)
void k_s2(const int* __restrict__ ei, const float* __restrict__ deg,
          const float* __restrict__ zpack, const float* __restrict__ nh,
          const float* __restrict__ W1, const float* __restrict__ b1,
          const float* __restrict__ a1, const float* __restrict__ g1,
          const float* __restrict__ be1,
          float* m1, float* aggzE, float* s1E) {
    const int blk = blockIdx.x;
    const int tid = threadIdx.x;
    if (blk < MLP_BLOCKS) {
        mlp_body(blk, tid, nh, W1, b1, a1, g1, be1, m1);
    } else {
        const int base = (blk - MLP_BLOCKS) * AGG1_PER_BLOCK;
        #pragma unroll
        for (int i = 0; i < 4; ++i) {
            const int it = i * 256 + tid;
            if (it < AGG1_PER_BLOCK) {
                const int t = base + it;
                if (t < EE * BB) agg1_item(t, ei, deg, zpack, aggzE, s1E);
            }
        }
    }
}

__global__ __launch_bounds__(256, 4)
void k_s3(const float* __restrict__ W2, const float* __restrict__ m1,
          const float* __restrict__ b2, const float* __restrict__ a2,
          const float* __restrict__ g2, const float* __restrict__ be2,
          const float* __restrict__ Wo,
          const int* __restrict__ ei, const float* __restrict__ deg,
          const float* __restrict__ zpack, const float* __restrict__ aggzE,
          float* aggz2E, float* ysum) {
    __shared__ float accs[4][80][16];
    const int blk = blockIdx.x;
    const int tid = threadIdx.x;
    {
        const int base = blk * AGG2_PER_BLOCK;
        #pragma unroll
        for (int i = 0; i < 3; ++i) {
            const int it = i * 256 + tid;
            if (it < AGG2_PER_BLOCK) agg2_item(base + it, ei, deg, zpack, aggzE, aggz2E);
        }
    }
    stream_body(blk, tid, accs, W2, m1, b2, a2, g2, be2, Wo, ysum);
}

__global__ __launch_bounds__(256)
void k_fin(const float* __restrict__ ysum, const float* __restrict__ aggzE,
           const float* __restrict__ aggz2E, const float* __restrict__ s1E,
           const float* __restrict__ deg, const float* __restrict__ zpack,
           const float* __restrict__ cst, float* __restrict__ y) {
    const int t = blockIdx.x * 256 + threadIdx.x;
    if (t < BB * NN) fin_item(t, ysum, aggzE, aggz2E, s1E, deg, zpack, cst, y);
}

// ---------------- launcher ------------------------------------------------------

extern "C" void kernel_launch(void* const* d_in, const int* in_sizes, int n_in,
                              void* d_out, int out_size, void* d_ws, size_t ws_size,
                              hipStream_t stream) {
    const float* x   = (const float*)d_in[0];
    const float* svp = (const float*)d_in[1];
    const int*   ei  = (const int*)d_in[2];
    const float* Wih = (const float*)d_in[3];
    // d_in[4] = Whh unused (hidden == 0)
    const float* bih = (const float*)d_in[5];
    const float* bhh = (const float*)d_in[6];
    const float* Wg1 = (const float*)d_in[7];
    const float* bg1 = (const float*)d_in[8];
    const float* Wg2 = (const float*)d_in[9];
    const float* bg2 = (const float*)d_in[10];
    const float* W1  = (const float*)d_in[11];
    const float* b1  = (const float*)d_in[12];
    const float* a1  = (const float*)d_in[13];
    const float* g1  = (const float*)d_in[14];
    const float* be1 = (const float*)d_in[15];
    const float* W2  = (const float*)d_in[16];
    const float* b2  = (const float*)d_in[17];
    const float* a2  = (const float*)d_in[18];
    const float* g2  = (const float*)d_in[19];
    const float* be2 = (const float*)d_in[20];
    const float* Wo  = (const float*)d_in[21];
    const float* bo  = (const float*)d_in[22];
    float* out = (float*)d_out;

    float* ws      = (float*)d_ws;
    float* deg     = ws;                    // NN
    float* s1E     = deg + NN;              // NN
    float* aggzE   = s1E + NN;              // BB*NN
    float* aggz2E  = aggzE + BB * NN;       // BB*NN
    float* zpack   = aggz2E + BB * NN;      // BB*NN
    float* ysum    = zpack + BB * NN;       // BB*NN
    float* nh      = ysum + BB * NN;        // BB*HID
    float* m1      = nh + BB * HID;         // BB*M1D
    float* cst     = m1 + BB * M1D;         // 3

    hipMemsetAsync(ws, 0, (size_t)(2 * NN) * sizeof(float), stream);

    float* outNH = out + BB * NN;
    k_s1<<<dim3(GRU_BLOCKS + DEG_BLOCKS + 1 + ZPACK_BLOCKS + ZERO_BLOCKS),
           dim3(256), 0, stream>>>(
        ei, x, svp, Wih, bih, bhh, Wg1, bg1, Wg2, bg2, Wo, bo,
        deg, nh, outNH, cst, zpack, aggzE /*zerobase*/);

    void* args[] = {
        (void*)&W2, (void*)&m1, (void*)&b2, (void*)&a2, (void*)&g2, (void*)&be2,
        (void*)&Wo, (void*)&ei, (void*)&deg, (void*)&zpack, (void*)&aggzE,
        (void*)&aggz2E, (void*)&s1E, (void*)&ysum, (void*)&nh, (void*)&W1,
        (void*)&b1, (void*)&a1, (void*)&g1, (void*)&be1, (void*)&cst, (void*)&out
    };
    hipError_t cerr = hipLaunchCooperativeKernel((const void*)k_coop,
                          dim3(COOP_BLOCKS), dim3(256), args, 0, stream);
    if (cerr != hipSuccess) {
        // deterministic fallback: proven 3-kernel chain
        k_s2<<<dim3(MLP_BLOCKS + AGG1_BLOCKS), dim3(256), 0, stream>>>(
            ei, deg, zpack, nh, W1, b1, a1, g1, be1, m1, aggzE, s1E);
        k_s3<<<dim3(COOP_BLOCKS), dim3(256), 0, stream>>>(
            W2, m1, b2, a2, g2, be2, Wo, ei, deg, zpack, aggzE, aggz2E, ysum);
        k_fin<<<dim3((BB * NN + 255) / 256), dim3(256), 0, stream>>>(
            ysum, aggzE, aggz2E, s1E, deg, zpack, cst, out);
    }
}

// Round 10
// 110.760 us; speedup vs baseline: 3.1092x; 3.1092x over previous
//
#include <hip/hip_runtime.h>
#include <hip/hip_bf16.h>

#define NN 5000
#define BB 16
#define EE 40000
#define INF 128
#define HID 512
#define M1D 1024
#define EPSV 1e-5f

typedef float f4 __attribute__((ext_vector_type(4)));

__device__ __forceinline__ float dot4(f4 a, f4 b) {
    return fmaf(a.x, b.x, fmaf(a.y, b.y, fmaf(a.z, b.z, a.w * b.w)));
}
// plain vector load for the W2 stream (A/B vs nontemporal: R10 experiment)
__device__ __forceinline__ f4 stload(const float* p) {
    return *(const f4*)p;
}
// DPP cross-lane (VALU, no DS pipe): xor1 = quad_perm[1,0,3,2], xor2 = quad_perm[2,3,0,1],
// xor8 = row_ror:8 (rotate by 8 within a 16-lane row == xor 8)
__device__ __forceinline__ float dpp_xor1(float x) {
    return __int_as_float(__builtin_amdgcn_update_dpp(0, __float_as_int(x), 0xB1, 0xF, 0xF, true));
}
__device__ __forceinline__ float dpp_xor2(float x) {
    return __int_as_float(__builtin_amdgcn_update_dpp(0, __float_as_int(x), 0x4E, 0xF, 0xF, true));
}
__device__ __forceinline__ float dpp_xor8(float x) {
    return __int_as_float(__builtin_amdgcn_update_dpp(0, __float_as_int(x), 0x128, 0xF, 0xF, true));
}

// ---------------- S1: GRU | deg-atomics | consts | zpack | zero ---------------
#define GRU_BLOCKS 128
#define DEG_BLOCKS 157
#define ZPACK_BLOCKS 313
#define ZERO_BLOCKS 157
// roles: [0,128) GRU | [128,285) deg | 285 consts | [286,599) zpack | [599,756) zero

__global__ __launch_bounds__(256)
void k_s1(const int* __restrict__ ei, const float* __restrict__ x,
          const float* __restrict__ svp,
          const float* __restrict__ Wih, const float* __restrict__ bih,
          const float* __restrict__ bhh,
          const float* __restrict__ Wg1, const float* __restrict__ bg1,
          const float* __restrict__ Wg2, const float* __restrict__ bg2,
          const float* __restrict__ Wo, const float* __restrict__ bo,
          float* __restrict__ deg, float* __restrict__ nh,
          float* __restrict__ outNH, float* __restrict__ cst,
          float* __restrict__ zpack, float* __restrict__ zerobase) {
    const int blk = blockIdx.x;
    const int tid = threadIdx.x;

    if (blk < GRU_BLOCKS) {
        // GRU with h=0: 4 lanes per (b,h), K=128 split 4 ways
        const int t = blk * 256 + tid;
        const int q = t & 3, idx = t >> 2;
        const int b = idx >> 9, h = idx & 511;
        const float* xb = x + b * INF;
        const float* wr = Wih + (size_t)h * INF;
        const float* wz = Wih + (size_t)(HID + h) * INF;
        const float* wg = Wih + (size_t)(2 * HID + h) * INF;
        float ir = 0.f, iz = 0.f, ig = 0.f;
        #pragma unroll 8
        for (int i = 0; i < 8; ++i) {
            const int k0 = i * 16 + q * 4;
            const f4 xv = *(const f4*)(xb + k0);
            ir += dot4(xv, *(const f4*)(wr + k0));
            iz += dot4(xv, *(const f4*)(wz + k0));
            ig += dot4(xv, *(const f4*)(wg + k0));
        }
        ir += __shfl_xor(ir, 1); ir += __shfl_xor(ir, 2);
        iz += __shfl_xor(iz, 1); iz += __shfl_xor(iz, 2);
        ig += __shfl_xor(ig, 1); ig += __shfl_xor(ig, 2);
        if (q == 0) {
            ir += bih[h]; iz += bih[HID + h]; ig += bih[2 * HID + h];
            float r  = 1.f / (1.f + expf(-(ir + bhh[h])));
            float z  = 1.f / (1.f + expf(-(iz + bhh[HID + h])));
            float nv = tanhf(ig + r * bhh[2 * HID + h]);
            float v  = (1.f - z) * nv;
            nh[idx] = v;
            outNH[idx] = v;
        }
    } else if (blk < GRU_BLOCKS + DEG_BLOCKS) {
        const int e = (blk - GRU_BLOCKS) * 256 + tid;
        if (e < EE) atomicAdd(&deg[ei[EE + e]], 1.0f);
    } else if (blk == GRU_BLOCKS + DEG_BLOCKS) {
        // consts: U, V, C0
        __shared__ float su[128], sv[128], sc[128];
        const int g = tid;
        if (g < 128) {
            float t = 0.f;
            for (int c = 0; c < 128; ++c) t = fmaf(Wg2[g * 128 + c], Wo[16 + c], t);
            su[g] = Wg1[g] * t;
            sv[g] = bg1[g] * t;
            sc[g] = bg2[g] * Wo[16 + g];
        }
        __syncthreads();
        for (int s = 64; s > 0; s >>= 1) {
            if (g < s) { su[g] += su[g + s]; sv[g] += sv[g + s]; sc[g] += sc[g + s]; }
            __syncthreads();
        }
        if (g == 0) { cst[0] = su[0]; cst[1] = sv[0]; cst[2] = sc[0] + bo[0]; }
    } else if (blk < GRU_BLOCKS + DEG_BLOCKS + 1 + ZPACK_BLOCKS) {
        // zpack[n*16+b] = z[b][n]
        const int t = (blk - (GRU_BLOCKS + DEG_BLOCKS + 1)) * 256 + tid;
        if (t < NN * BB) {
            const int n = t >> 4, b = t & 15;
            zpack[t] = svp[b * (NN * 3) + 3 * n + 2];
        }
    } else {
        // zero aggzE + aggz2E (contiguous 160000 floats = 40000 f4; 157*256=40192 covers)
        const int t = (blk - (GRU_BLOCKS + DEG_BLOCKS + 1 + ZPACK_BLOCKS)) * 256 + tid;
        if (t < 2 * BB * NN / 4) ((f4*)zerobase)[t] = (f4)(0.f);
    }
}

// ---------------- S2: agg1 | MLP1 ---------------------------------------------
#define AGG1_BLOCKS 2500
#define MLP_BLOCKS 256

__global__ __launch_bounds__(256)
void k_s2(const int* __restrict__ ei, const float* __restrict__ deg,
          const float* __restrict__ zpack, const float* __restrict__ nh,
          const float* __restrict__ W1, const float* __restrict__ b1,
          const float* __restrict__ a1, const float* __restrict__ g1,
          const float* __restrict__ be1,
          float* __restrict__ m1, float* __restrict__ aggzE, float* __restrict__ s1E) {
    const int blk = blockIdx.x;
    const int tid = threadIdx.x;

    if (blk < AGG1_BLOCKS) {
        const int t = blk * 256 + tid;
        const int e = t >> 4, b = t & 15;
        const int s = ei[e], d = ei[EE + e];
        const float w = rsqrtf(1.f + deg[s]) * rsqrtf(1.f + deg[d]);
        atomicAdd(&aggzE[d * 16 + b], w * zpack[s * 16 + b]);
        if (b == 0) atomicAdd(&s1E[d], w);
    } else {
        const int t = (blk - AGG1_BLOCKS) * 256 + tid;
        const int q = t & 3, idx = t >> 2;
        const int b = idx >> 10, i = idx & 1023;
        const float* hb = nh + b * HID;
        const float* wr = W1 + (size_t)i * HID;
        float acc = 0.f;
        #pragma unroll 8
        for (int ii = 0; ii < 32; ++ii) {
            const int k0 = ii * 16 + q * 4;
            acc += dot4(*(const f4*)(hb + k0), *(const f4*)(wr + k0));
        }
        acc += __shfl_xor(acc, 1); acc += __shfl_xor(acc, 2);
        if (q == 0) {
            acc += b1[i];
            float v = acc >= 0.f ? acc : a1[i] * acc;
            m1[idx] = v * (1.f / sqrtf(1.f + EPSV)) * g1[i] + be1[i];
        }
    }
}

// ---------------- S3: k_big main (full W2 stream) | agg2 ----------------------
#define BIG_BLOCKS 1000
#define AGG2_BLOCKS 2500

__global__ __launch_bounds__(256, 4)
void k_s3(const float* __restrict__ W2, const float* __restrict__ m1,
          const float* __restrict__ b2, const float* __restrict__ a2,
          const float* __restrict__ g2, const float* __restrict__ be2,
          const float* __restrict__ Wo,
          const int* __restrict__ ei, const float* __restrict__ deg,
          const float* __restrict__ zpack, const float* __restrict__ aggzE,
          float* __restrict__ aggz2E, float* __restrict__ ysum) {
    __shared__ float accs[4][80][16];
    const int blk = blockIdx.x;
    const int tid = threadIdx.x;

    if (blk < BIG_BLOCKS) {
        const int w = tid >> 6, l = tid & 63;
        const int koff = w * 256 + l * 4;
        const int n0 = blk * 5;
        const int jbase = n0 * 16;

        float4 m1r[16];
        #pragma unroll
        for (int b = 0; b < 16; ++b)
            m1r[b] = *(const float4*)(m1 + b * M1D + koff);

        const int hi0 = l & 1, hi1 = (l >> 1) & 1, hi2 = (l >> 2) & 1, hi3 = (l >> 3) & 1;
        const int brev = ((l & 1) << 3) | ((l & 2) << 1) | ((l & 4) >> 1) | ((l & 8) >> 3);

        const float* wp = W2 + (size_t)jbase * M1D + koff;
        // 3-deep prefetch pipeline (plain loads this round — nt A/B)
        f4 w0 = stload(wp);
        f4 w1 = stload(wp + M1D);
        f4 w2v = stload(wp + 2 * M1D);
        for (int jj = 0; jj < 80; ++jj) {
            const int jn = (jj + 3 < 80) ? (jj + 3) : 79;
            const f4 wn = stload(wp + (size_t)jn * M1D);
            float acc[16];
            #pragma unroll
            for (int b = 0; b < 16; ++b)
                acc[b] = fmaf(w0.x, m1r[b].x, fmaf(w0.y, m1r[b].y,
                         fmaf(w0.z, m1r[b].z, w0.w * m1r[b].w)));
            // value-halving butterfly; xor1/xor2/xor8 on the VALU via DPP
            float r8[8];
            #pragma unroll
            for (int i = 0; i < 8; ++i) {
                float keep = hi0 ? acc[8 + i] : acc[i];
                float send = hi0 ? acc[i]     : acc[8 + i];
                r8[i] = keep + dpp_xor1(send);
            }
            float r4[4];
            #pragma unroll
            for (int i = 0; i < 4; ++i) {
                float keep = hi1 ? r8[4 + i] : r8[i];
                float send = hi1 ? r8[i]     : r8[4 + i];
                r4[i] = keep + dpp_xor2(send);
            }
            float r2[2];
            #pragma unroll
            for (int i = 0; i < 2; ++i) {
                float keep = hi2 ? r4[2 + i] : r4[i];
                float send = hi2 ? r4[i]     : r4[2 + i];
                r2[i] = keep + __shfl_xor(send, 4, 64);
            }
            float keep = hi3 ? r2[1] : r2[0];
            float send = hi3 ? r2[0] : r2[1];
            float r1 = keep + dpp_xor8(send);
            r1 += __shfl_xor(r1, 16, 64);
            r1 += __shfl_xor(r1, 32, 64);
            if (l < 16) accs[w][jj][brev] = r1;
            w0 = w1; w1 = w2v; w2v = wn;
        }
        __syncthreads();

        if (tid < 80) {
            const int nl = tid >> 4, b = tid & 15;
            const float invs = 1.f / sqrtf(1.f + EPSV);
            float sum = 0.f;
            #pragma unroll
            for (int kk = 0; kk < 16; ++kk) {
                const int rloc = nl * 16 + kk;
                const int j = jbase + rloc;
                float a = accs[0][rloc][b] + accs[1][rloc][b]
                        + accs[2][rloc][b] + accs[3][rloc][b] + b2[j];
                float v = a >= 0.f ? a : a2[j] * a;
                float val = v * invs * g2[j] + be2[j];
                sum = fmaf(val, Wo[kk], sum);
            }
            ysum[n0 * 16 + tid] = sum;   // [n][b] layout
        }
    } else {
        // agg2: aggz2E[d*16+b] += w * (aggzE[s*16+b] + d2s*z[s,b])
        const int t = (blk - BIG_BLOCKS) * 256 + tid;
        const int e = t >> 4, b = t & 15;
        const int s = ei[e], d = ei[EE + e];
        const float degs = deg[s];
        const float d2s = 1.f / (1.f + degs);
        const float w = rsqrtf(1.f + degs) * rsqrtf(1.f + deg[d]);
        const float A1s = aggzE[s * 16 + b] + d2s * zpack[s * 16 + b];
        atomicAdd(&aggz2E[d * 16 + b], w * A1s);
    }
}

// ---------------- S4: final epilogue (coalesced reads) ------------------------
__global__ __launch_bounds__(256)
void k_fin(const float* __restrict__ ysum, const float* __restrict__ aggzE,
           const float* __restrict__ aggz2E, const float* __restrict__ s1E,
           const float* __restrict__ deg, const float* __restrict__ zpack,
           const float* __restrict__ cst, float* __restrict__ y) {
    const int t = blockIdx.x * 256 + threadIdx.x;
    if (t >= BB * NN) return;
    const int n = t >> 4, b = t & 15;
    const float U = cst[0], V = cst[1], C0 = cst[2];
    const float d2 = 1.f / (1.f + deg[n]);
    const float z  = zpack[t];
    const float A1 = aggzE[t] + d2 * z;
    const float A2 = aggz2E[t] + d2 * A1;
    const float S1v = s1E[n] + d2;
    y[b * NN + n] = ysum[t] + U * A2 + V * S1v + C0;
}

// ---------------- launcher ------------------------------------------------------

extern "C" void kernel_launch(void* const* d_in, const int* in_sizes, int n_in,
                              void* d_out, int out_size, void* d_ws, size_t ws_size,
                              hipStream_t stream) {
    const float* x   = (const float*)d_in[0];
    const float* svp = (const float*)d_in[1];
    const int*   ei  = (const int*)d_in[2];
    const float* Wih = (const float*)d_in[3];
    // d_in[4] = Whh unused (hidden == 0)
    const float* bih = (const float*)d_in[5];
    const float* bhh = (const float*)d_in[6];
    const float* Wg1 = (const float*)d_in[7];
    const float* bg1 = (const float*)d_in[8];
    const float* Wg2 = (const float*)d_in[9];
    const float* bg2 = (const float*)d_in[10];
    const float* W1  = (const float*)d_in[11];
    const float* b1  = (const float*)d_in[12];
    const float* a1  = (const float*)d_in[13];
    const float* g1  = (const float*)d_in[14];
    const float* be1 = (const float*)d_in[15];
    const float* W2  = (const float*)d_in[16];
    const float* b2  = (const float*)d_in[17];
    const float* a2  = (const float*)d_in[18];
    const float* g2  = (const float*)d_in[19];
    const float* be2 = (const float*)d_in[20];
    const float* Wo  = (const float*)d_in[21];
    const float* bo  = (const float*)d_in[22];
    float* out = (float*)d_out;

    float* ws      = (float*)d_ws;
    float* deg     = ws;                    // NN
    float* s1E     = deg + NN;              // NN
    float* aggzE   = s1E + NN;              // BB*NN
    float* aggz2E  = aggzE + BB * NN;       // BB*NN
    float* zpack   = aggz2E + BB * NN;      // BB*NN
    float* ysum    = zpack + BB * NN;       // BB*NN
    float* nh      = ysum + BB * NN;        // BB*HID
    float* m1      = nh + BB * HID;         // BB*M1D
    float* cst     = m1 + BB * M1D;         // 3

    // zero atomic targets deg + s1E (aggzE/aggz2E zeroed by S1 zero-role blocks)
    hipMemsetAsync(ws, 0, (size_t)(2 * NN) * sizeof(float), stream);

    k_s1<<<dim3(GRU_BLOCKS + DEG_BLOCKS + 1 + ZPACK_BLOCKS + ZERO_BLOCKS),
           dim3(256), 0, stream>>>(
        ei, x, svp, Wih, bih, bhh, Wg1, bg1, Wg2, bg2, Wo, bo,
        deg, nh, out + BB * NN, cst, zpack, aggzE /*zerobase*/);

    k_s2<<<dim3(AGG1_BLOCKS + MLP_BLOCKS), dim3(256), 0, stream>>>(
        ei, deg, zpack, nh, W1, b1, a1, g1, be1, m1, aggzE, s1E);

    k_s3<<<dim3(BIG_BLOCKS + AGG2_BLOCKS), dim3(256), 0, stream>>>(
        W2, m1, b2, a2, g2, be2, Wo, ei, deg, zpack, aggzE, aggz2E, ysum);

    k_fin<<<dim3((BB * NN + 255) / 256), dim3(256), 0, stream>>>(
        ysum, aggzE, aggz2E, s1E, deg, zpack, cst, out);
}

// Round 11
// 103.628 us; speedup vs baseline: 3.3231x; 1.0688x over previous
//
#include <hip/hip_runtime.h>
#include <hip/hip_bf16.h>

#define NN 5000
#define BB 16
#define EE 40000
#define INF 128
#define HID 512
#define M1D 1024
#define EPSV 1e-5f

typedef float f4 __attribute__((ext_vector_type(4)));

__device__ __forceinline__ float dot4(f4 a, f4 b) {
    return fmaf(a.x, b.x, fmaf(a.y, b.y, fmaf(a.z, b.z, a.w * b.w)));
}
__device__ __forceinline__ f4 ntload(const float* p) {
    return __builtin_nontemporal_load((const f4*)p);
}
// DPP cross-lane (VALU, no DS pipe): xor1 = quad_perm[1,0,3,2], xor2 = quad_perm[2,3,0,1],
// xor8 = row_ror:8 (rotate by 8 within a 16-lane row == xor 8)
__device__ __forceinline__ float dpp_xor1(float x) {
    return __int_as_float(__builtin_amdgcn_update_dpp(0, __float_as_int(x), 0xB1, 0xF, 0xF, true));
}
__device__ __forceinline__ float dpp_xor2(float x) {
    return __int_as_float(__builtin_amdgcn_update_dpp(0, __float_as_int(x), 0x4E, 0xF, 0xF, true));
}
__device__ __forceinline__ float dpp_xor8(float x) {
    return __int_as_float(__builtin_amdgcn_update_dpp(0, __float_as_int(x), 0x128, 0xF, 0xF, true));
}

// ---------------- S1: GRU | deg-atomics | consts | zpack ----------------------
#define GRU_BLOCKS 128
#define DEG_BLOCKS 157
#define ZPACK_BLOCKS 313
// roles: [0,128) GRU | [128,285) deg | 285 consts | [286,599) zpack

__global__ __launch_bounds__(256)
void k_s1(const int* __restrict__ ei, const float* __restrict__ x,
          const float* __restrict__ svp,
          const float* __restrict__ Wih, const float* __restrict__ bih,
          const float* __restrict__ bhh,
          const float* __restrict__ Wg1, const float* __restrict__ bg1,
          const float* __restrict__ Wg2, const float* __restrict__ bg2,
          const float* __restrict__ Wo, const float* __restrict__ bo,
          float* __restrict__ deg, float* __restrict__ nh,
          float* __restrict__ outNH, float* __restrict__ cst,
          float* __restrict__ zpack) {
    const int blk = blockIdx.x;
    const int tid = threadIdx.x;

    if (blk < GRU_BLOCKS) {
        // GRU with h=0: 4 lanes per (b,h), K=128 split 4 ways
        const int t = blk * 256 + tid;
        const int q = t & 3, idx = t >> 2;
        const int b = idx >> 9, h = idx & 511;
        const float* xb = x + b * INF;
        const float* wr = Wih + (size_t)h * INF;
        const float* wz = Wih + (size_t)(HID + h) * INF;
        const float* wg = Wih + (size_t)(2 * HID + h) * INF;
        float ir = 0.f, iz = 0.f, ig = 0.f;
        #pragma unroll 8
        for (int i = 0; i < 8; ++i) {
            const int k0 = i * 16 + q * 4;
            const f4 xv = *(const f4*)(xb + k0);
            ir += dot4(xv, *(const f4*)(wr + k0));
            iz += dot4(xv, *(const f4*)(wz + k0));
            ig += dot4(xv, *(const f4*)(wg + k0));
        }
        ir += __shfl_xor(ir, 1); ir += __shfl_xor(ir, 2);
        iz += __shfl_xor(iz, 1); iz += __shfl_xor(iz, 2);
        ig += __shfl_xor(ig, 1); ig += __shfl_xor(ig, 2);
        if (q == 0) {
            ir += bih[h]; iz += bih[HID + h]; ig += bih[2 * HID + h];
            float r  = 1.f / (1.f + expf(-(ir + bhh[h])));
            float z  = 1.f / (1.f + expf(-(iz + bhh[HID + h])));
            float nv = tanhf(ig + r * bhh[2 * HID + h]);
            float v  = (1.f - z) * nv;
            nh[idx] = v;
            outNH[idx] = v;
        }
    } else if (blk < GRU_BLOCKS + DEG_BLOCKS) {
        const int e = (blk - GRU_BLOCKS) * 256 + tid;
        if (e < EE) atomicAdd(&deg[ei[EE + e]], 1.0f);
    } else if (blk == GRU_BLOCKS + DEG_BLOCKS) {
        // consts: U, V, C0
        __shared__ float su[128], sv[128], sc[128];
        const int g = tid;
        if (g < 128) {
            float t = 0.f;
            for (int c = 0; c < 128; ++c) t = fmaf(Wg2[g * 128 + c], Wo[16 + c], t);
            su[g] = Wg1[g] * t;
            sv[g] = bg1[g] * t;
            sc[g] = bg2[g] * Wo[16 + g];
        }
        __syncthreads();
        for (int s = 64; s > 0; s >>= 1) {
            if (g < s) { su[g] += su[g + s]; sv[g] += sv[g + s]; sc[g] += sc[g + s]; }
            __syncthreads();
        }
        if (g == 0) { cst[0] = su[0]; cst[1] = sv[0]; cst[2] = sc[0] + bo[0]; }
    } else {
        // zpack[n*16+b] = z[b][n]
        const int t = (blk - (GRU_BLOCKS + DEG_BLOCKS + 1)) * 256 + tid;
        if (t < NN * BB) {
            const int n = t >> 4, b = t & 15;
            zpack[t] = svp[b * (NN * 3) + 3 * n + 2];
        }
    }
}

// ---------------- S2: agg1 (4 items/thread) | MLP1 ----------------------------
#define AGG1_BLOCKS 625     // 625 * 1024 = 640000 exactly
#define MLP_BLOCKS 256

__global__ __launch_bounds__(256)
void k_s2(const int* __restrict__ ei, const float* __restrict__ deg,
          const float* __restrict__ zpack, const float* __restrict__ nh,
          const float* __restrict__ W1, const float* __restrict__ b1,
          const float* __restrict__ a1, const float* __restrict__ g1,
          const float* __restrict__ be1,
          float* __restrict__ m1, float* __restrict__ aggzE, float* __restrict__ s1E) {
    const int blk = blockIdx.x;
    const int tid = threadIdx.x;

    if (blk < AGG1_BLOCKS) {
        const int base = blk * 1024;
        #pragma unroll
        for (int i = 0; i < 4; ++i) {
            const int t = base + i * 256 + tid;
            const int e = t >> 4, b = t & 15;
            const int s = ei[e], d = ei[EE + e];
            const float w = rsqrtf(1.f + deg[s]) * rsqrtf(1.f + deg[d]);
            atomicAdd(&aggzE[d * 16 + b], w * zpack[s * 16 + b]);
            if (b == 0) atomicAdd(&s1E[d], w);
        }
    } else {
        const int t = (blk - AGG1_BLOCKS) * 256 + tid;
        const int q = t & 3, idx = t >> 2;
        const int b = idx >> 10, i = idx & 1023;
        const float* hb = nh + b * HID;
        const float* wr = W1 + (size_t)i * HID;
        float acc = 0.f;
        #pragma unroll 8
        for (int ii = 0; ii < 32; ++ii) {
            const int k0 = ii * 16 + q * 4;
            acc += dot4(*(const f4*)(hb + k0), *(const f4*)(wr + k0));
        }
        acc += __shfl_xor(acc, 1); acc += __shfl_xor(acc, 2);
        if (q == 0) {
            acc += b1[i];
            float v = acc >= 0.f ? acc : a1[i] * acc;
            m1[idx] = v * (1.f / sqrtf(1.f + EPSV)) * g1[i] + be1[i];
        }
    }
}

// ---------------- S3: full W2 stream | agg2 (4 items/thread) ------------------
#define BIG_BLOCKS 1000
#define AGG2_BLOCKS 625     // 625 * 1024 = 640000 exactly

__global__ __launch_bounds__(256, 4)
void k_s3(const float* __restrict__ W2, const float* __restrict__ m1,
          const float* __restrict__ b2, const float* __restrict__ a2,
          const float* __restrict__ g2, const float* __restrict__ be2,
          const float* __restrict__ Wo,
          const int* __restrict__ ei, const float* __restrict__ deg,
          const float* __restrict__ zpack, const float* __restrict__ aggzE,
          float* __restrict__ aggz2E, float* __restrict__ ysum) {
    __shared__ float accs[4][80][16];
    const int blk = blockIdx.x;
    const int tid = threadIdx.x;

    if (blk < BIG_BLOCKS) {
        const int w = tid >> 6, l = tid & 63;
        const int koff = w * 256 + l * 4;
        const int n0 = blk * 5;
        const int jbase = n0 * 16;

        float4 m1r[16];
        #pragma unroll
        for (int b = 0; b < 16; ++b)
            m1r[b] = *(const float4*)(m1 + b * M1D + koff);

        const int hi0 = l & 1, hi1 = (l >> 1) & 1, hi2 = (l >> 2) & 1, hi3 = (l >> 3) & 1;
        const int brev = ((l & 1) << 3) | ((l & 2) << 1) | ((l & 4) >> 1) | ((l & 8) >> 3);

        const float* wp = W2 + (size_t)jbase * M1D + koff;
        // 3-deep prefetch pipeline, nontemporal loads
        f4 w0 = ntload(wp);
        f4 w1 = ntload(wp + M1D);
        f4 w2v = ntload(wp + 2 * M1D);
        for (int jj = 0; jj < 80; ++jj) {
            const int jn = (jj + 3 < 80) ? (jj + 3) : 79;
            const f4 wn = ntload(wp + (size_t)jn * M1D);
            float acc[16];
            #pragma unroll
            for (int b = 0; b < 16; ++b)
                acc[b] = fmaf(w0.x, m1r[b].x, fmaf(w0.y, m1r[b].y,
                         fmaf(w0.z, m1r[b].z, w0.w * m1r[b].w)));
            // value-halving butterfly; xor1/xor2/xor8 on the VALU via DPP
            float r8[8];
            #pragma unroll
            for (int i = 0; i < 8; ++i) {
                float keep = hi0 ? acc[8 + i] : acc[i];
                float send = hi0 ? acc[i]     : acc[8 + i];
                r8[i] = keep + dpp_xor1(send);
            }
            float r4[4];
            #pragma unroll
            for (int i = 0; i < 4; ++i) {
                float keep = hi1 ? r8[4 + i] : r8[i];
                float send = hi1 ? r8[i]     : r8[4 + i];
                r4[i] = keep + dpp_xor2(send);
            }
            float r2[2];
            #pragma unroll
            for (int i = 0; i < 2; ++i) {
                float keep = hi2 ? r4[2 + i] : r4[i];
                float send = hi2 ? r4[i]     : r4[2 + i];
                r2[i] = keep + __shfl_xor(send, 4, 64);
            }
            float keep = hi3 ? r2[1] : r2[0];
            float send = hi3 ? r2[0] : r2[1];
            float r1 = keep + dpp_xor8(send);
            r1 += __shfl_xor(r1, 16, 64);
            r1 += __shfl_xor(r1, 32, 64);
            if (l < 16) accs[w][jj][brev] = r1;
            w0 = w1; w1 = w2v; w2v = wn;
        }
        __syncthreads();

        if (tid < 80) {
            const int nl = tid >> 4, b = tid & 15;
            const float invs = 1.f / sqrtf(1.f + EPSV);
            float sum = 0.f;
            #pragma unroll
            for (int kk = 0; kk < 16; ++kk) {
                const int rloc = nl * 16 + kk;
                const int j = jbase + rloc;
                float a = accs[0][rloc][b] + accs[1][rloc][b]
                        + accs[2][rloc][b] + accs[3][rloc][b] + b2[j];
                float v = a >= 0.f ? a : a2[j] * a;
                float val = v * invs * g2[j] + be2[j];
                sum = fmaf(val, Wo[kk], sum);
            }
            ysum[n0 * 16 + tid] = sum;   // [n][b] layout
        }
    } else {
        // agg2: 4 items/thread
        const int base = (blk - BIG_BLOCKS) * 1024;
        #pragma unroll
        for (int i = 0; i < 4; ++i) {
            const int t = base + i * 256 + tid;
            const int e = t >> 4, b = t & 15;
            const int s = ei[e], d = ei[EE + e];
            const float degs = deg[s];
            const float d2s = 1.f / (1.f + degs);
            const float w = rsqrtf(1.f + degs) * rsqrtf(1.f + deg[d]);
            const float A1s = aggzE[s * 16 + b] + d2s * zpack[s * 16 + b];
            atomicAdd(&aggz2E[d * 16 + b], w * A1s);
        }
    }
}

// ---------------- S4: final epilogue (coalesced reads) ------------------------
__global__ __launch_bounds__(256)
void k_fin(const float* __restrict__ ysum, const float* __restrict__ aggzE,
           const float* __restrict__ aggz2E, const float* __restrict__ s1E,
           const float* __restrict__ deg, const float* __restrict__ zpack,
           const float* __restrict__ cst, float* __restrict__ y) {
    const int t = blockIdx.x * 256 + threadIdx.x;
    if (t >= BB * NN) return;
    const int n = t >> 4, b = t & 15;
    const float U = cst[0], V = cst[1], C0 = cst[2];
    const float d2 = 1.f / (1.f + deg[n]);
    const float z  = zpack[t];
    const float A1 = aggzE[t] + d2 * z;
    const float A2 = aggz2E[t] + d2 * A1;
    const float S1v = s1E[n] + d2;
    y[b * NN + n] = ysum[t] + U * A2 + V * S1v + C0;
}

// ---------------- launcher ------------------------------------------------------

extern "C" void kernel_launch(void* const* d_in, const int* in_sizes, int n_in,
                              void* d_out, int out_size, void* d_ws, size_t ws_size,
                              hipStream_t stream) {
    const float* x   = (const float*)d_in[0];
    const float* svp = (const float*)d_in[1];
    const int*   ei  = (const int*)d_in[2];
    const float* Wih = (const float*)d_in[3];
    // d_in[4] = Whh unused (hidden == 0)
    const float* bih = (const float*)d_in[5];
    const float* bhh = (const float*)d_in[6];
    const float* Wg1 = (const float*)d_in[7];
    const float* bg1 = (const float*)d_in[8];
    const float* Wg2 = (const float*)d_in[9];
    const float* bg2 = (const float*)d_in[10];
    const float* W1  = (const float*)d_in[11];
    const float* b1  = (const float*)d_in[12];
    const float* a1  = (const float*)d_in[13];
    const float* g1  = (const float*)d_in[14];
    const float* be1 = (const float*)d_in[15];
    const float* W2  = (const float*)d_in[16];
    const float* b2  = (const float*)d_in[17];
    const float* a2  = (const float*)d_in[18];
    const float* g2  = (const float*)d_in[19];
    const float* be2 = (const float*)d_in[20];
    const float* Wo  = (const float*)d_in[21];
    const float* bo  = (const float*)d_in[22];
    float* out = (float*)d_out;

    float* ws      = (float*)d_ws;
    float* deg     = ws;                    // NN
    float* s1E     = deg + NN;              // NN
    float* aggzE   = s1E + NN;              // BB*NN
    float* aggz2E  = aggzE + BB * NN;       // BB*NN
    float* zpack   = aggz2E + BB * NN;      // BB*NN
    float* ysum    = zpack + BB * NN;       // BB*NN
    float* nh      = ysum + BB * NN;        // BB*HID
    float* m1      = nh + BB * HID;         // BB*M1D
    float* cst     = m1 + BB * M1D;         // 3

    // zero ALL atomic targets in one shot: deg | s1E | aggzE | aggz2E (contiguous)
    hipMemsetAsync(ws, 0, (size_t)(2 * NN + 2 * BB * NN) * sizeof(float), stream);

    k_s1<<<dim3(GRU_BLOCKS + DEG_BLOCKS + 1 + ZPACK_BLOCKS), dim3(256), 0, stream>>>(
        ei, x, svp, Wih, bih, bhh, Wg1, bg1, Wg2, bg2, Wo, bo,
        deg, nh, out + BB * NN, cst, zpack);

    k_s2<<<dim3(AGG1_BLOCKS + MLP_BLOCKS), dim3(256), 0, stream>>>(
        ei, deg, zpack, nh, W1, b1, a1, g1, be1, m1, aggzE, s1E);

    k_s3<<<dim3(BIG_BLOCKS + AGG2_BLOCKS), dim3(256), 0, stream>>>(
        W2, m1, b2, a2, g2, be2, Wo, ei, deg, zpack, aggzE, aggz2E, ysum);

    k_fin<<<dim3((BB * NN + 255) / 256), dim3(256), 0, stream>>>(
        ysum, aggzE, aggz2E, s1E, deg, zpack, cst, out);
}